// Round 7
// baseline (153.122 us; speedup 1.0000x reference)
//
#include <hip/hip_runtime.h>

// HFCFilter: median-pad -> (identity hfc) -> per-(b,c) percentile norm on
// 1/256-quantized copy -> mask.
//
// Key facts exploited:
//  * output = mask ? (x - lo)/(hi - lo) : 0   (padding never reaches output)
//  * percentiles on trunc(res*256)/256 data -> exact via histogram rank scan
//  * (int)(x*1024)>>2 == (int)(x*256) exactly in fp32 -> ONE 1024-bin packed
//    histogram serves median (all pixels, lo16) + quantized percentile
//    (masked-in pixels, hi16). Per-block count 32768 < 2^16: no carry.
//  * x in [0,1) -> quantized mass lives in bins [0,256).
//  * stats fused into hist via last-arriving-block ticket. R6 lesson: the
//    "residue 7 mod 8" winner is the LAST arrival only if tickets start at
//    0 mod 8 -- the harness poisons ws to 0xAA (== 2 mod 8), so the winner
//    ran before 2 blocks had stored their partials (race seen only in the
//    post-timing re-validation). Fix: hipMemsetAsync(tickets,0) at launch
//    start (graph-capturable) -> winner is deterministically the 8th arrival.
//  * norm uses nontemporal stores (native ext_vector type; HIP float4 class
//    is rejected by the builtin) so the 101 MB out-stream doesn't evict the
//    L3-resident x/mask that norm re-reads.

#define B_       32
#define C_       3
#define BC       (B_ * C_)          // 96 channels
#define HW       (512 * 512)        // 262144 per channel
#define BINS     1024
#define QB       256                // quantized bins actually occupied
#define PCT_     3.0
#define CHUNKS1  8
#define CHUNKS3  32

typedef float f32x4 __attribute__((ext_vector_type(4)));

// Pass 1: per-(channel,chunk) private packed histogram -> partial slot.
// Last-arriving block per channel sums partials and computes lo/scale.
__global__ __launch_bounds__(256) void hist_stats_kernel(
        const float* __restrict__ x, const float* __restrict__ mask,
        unsigned* __restrict__ part, unsigned* __restrict__ tickets,
        float* __restrict__ loArr, float* __restrict__ scArr) {
    __shared__ unsigned h[BINS];        // hist; reused as 'tot' in stats
    __shared__ unsigned in1024[BINS];   // stats only
    __shared__ unsigned ps[256];        // scan workspace
    __shared__ unsigned s_rank;
    __shared__ unsigned s_mbin[2], s_mcum[2], s_mcnt[2];
    __shared__ unsigned s_qtot;
    __shared__ int      s_kb;
    __shared__ int      s_kv[4];

    const int ch    = blockIdx.x / CHUNKS1;
    const int chunk = blockIdx.x % CHUNKS1;
    const int b     = ch / C_;
    const int t     = threadIdx.x;

    for (int i = t; i < BINS; i += 256) h[i] = 0u;
    __syncthreads();

    const f32x4* x4 = (const f32x4*)x    + (size_t)ch * (HW / 4);
    const f32x4* m4 = (const f32x4*)mask + (size_t)b  * (HW / 4);
    const int per_chunk = (HW / 4) / CHUNKS1;   // 8192 float4
    const int base = chunk * per_chunk;

    for (int i = base + t; i < base + per_chunk; i += 256) {
        f32x4 xv = x4[i];
        f32x4 mv = m4[i];
#pragma unroll
        for (int j = 0; j < 4; ++j) {
            int mb = (int)(xv[j] * 1024.0f);
            mb = mb < 0 ? 0 : (mb > BINS - 1 ? BINS - 1 : mb);
            unsigned add = 1u + ((mv[j] > 0.5f) ? 0x10000u : 0u);
            atomicAdd(&h[mb], add);
        }
    }
    __syncthreads();

    unsigned* dst = part + (size_t)blockIdx.x * BINS;   // [ch][chunk][bin]
    for (int i = t; i < BINS; i += 256) dst[i] = h[i];

    // ---- ticket: last arrival (rank 7, tickets zeroed pre-launch) ----
    __threadfence();                      // release: partial visible device-wide
    if (t == 0) s_rank = atomicAdd(&tickets[ch], 1u);
    __syncthreads();
    if (s_rank != CHUNKS1 - 1) return;
    __threadfence();                      // acquire: see all 8 partials

    const unsigned* p = part + (size_t)ch * CHUNKS1 * BINS;
    for (int bin = t; bin < BINS; bin += 256) {
        unsigned tsum = 0, isum = 0;
#pragma unroll
        for (int c = 0; c < CHUNKS1; ++c) {
            unsigned v = p[(size_t)c * BINS + bin];
            tsum += v & 0xFFFFu;
            isum += v >> 16;
        }
        h[bin]      = tsum;               // reuse h as 'tot'
        in1024[bin] = isum;
    }
    __syncthreads();

    // ---- scan 1: totals, 4 bins/thread -> median crossing search ----
    unsigned b0 = h[4*t], b1 = h[4*t+1], b2 = h[4*t+2], b3 = h[4*t+3];
    unsigned s1 = b0 + b1, s2 = s1 + b2, S = s2 + b3;
    ps[t] = S;
    __syncthreads();
#pragma unroll
    for (int d = 1; d < 256; d <<= 1) {
        unsigned v = (t >= d) ? ps[t - d] : 0u;
        __syncthreads();
        ps[t] += v;
        __syncthreads();
    }
    {
        unsigned excl = ps[t] - S;
        unsigned cp[4] = {excl, excl + b0, excl + s1, excl + s2};
        unsigned ci[4] = {excl + b0, excl + s1, excl + s2, excl + S};
        const unsigned tg0 = HW / 2 - 1, tg1 = HW / 2;
#pragma unroll
        for (int j = 0; j < 4; ++j) {
            if (cp[j] <= tg0 && tg0 < ci[j]) {
                s_mbin[0] = 4*t + j; s_mcum[0] = cp[j]; s_mcnt[0] = ci[j] - cp[j];
            }
            if (cp[j] <= tg1 && tg1 < ci[j]) {
                s_mbin[1] = 4*t + j; s_mcum[1] = cp[j]; s_mcnt[1] = ci[j] - cp[j];
            }
        }
    }
    __syncthreads();

    if (t == 0) {
        const unsigned tgs[2] = {HW / 2 - 1, HW / 2};
        float vals[2];
#pragma unroll
        for (int ti = 0; ti < 2; ++ti) {
            float within = ((float)(tgs[ti] - s_mcum[ti]) + 0.5f) / (float)s_mcnt[ti];
            vals[ti] = ((float)s_mbin[ti] + within) * (1.0f / (float)BINS);
        }
        float med = 0.5f * (vals[0] + vals[1]);
        int kb = (int)((med + 0.2f) * 256.0f);
        s_kb = kb < 0 ? 0 : (kb > QB - 1 ? QB - 1 : kb);
    }
    __syncthreads();

    // ---- scan 2: masked-in counts folded to one q-bin per thread ----
    unsigned v = in1024[4*t] + in1024[4*t+1] + in1024[4*t+2] + in1024[4*t+3];
    ps[t] = v;
    __syncthreads();
#pragma unroll
    for (int d = 1; d < 256; d <<= 1) {
        unsigned u = (t >= d) ? ps[t - d] : 0u;
        __syncthreads();
        ps[t] += u;
        __syncthreads();
    }
    unsigned Q = ps[t];
    if (t == 255) s_qtot = Q;
    __syncthreads();

    {
        const unsigned mo = (unsigned)HW - s_qtot;   // masked-out pixel count
        const int kb = s_kb;
        unsigned cp = (Q - v) + ((t >  kb) ? mo : 0u);
        unsigned ci = Q       + ((t >= kb) ? mo : 0u);
        const double rlo = (PCT_ / 100.0) * (double)(HW - 1);
        const double rhi = ((100.0 - PCT_) / 100.0) * (double)(HW - 1);
        const unsigned ilo = (unsigned)rlo, ihi = (unsigned)rhi;
        const unsigned ranks[4] = {ilo, ilo + 1, ihi, ihi + 1};
#pragma unroll
        for (int ri = 0; ri < 4; ++ri)
            if (cp <= ranks[ri] && ranks[ri] < ci) s_kv[ri] = t;
    }
    __syncthreads();

    if (t == 0) {
        const double rlo = (PCT_ / 100.0) * (double)(HW - 1);
        const double rhi = ((100.0 - PCT_) / 100.0) * (double)(HW - 1);
        const unsigned ilo = (unsigned)rlo, ihi = (unsigned)rhi;
        float fl = (float)(rlo - (double)ilo);
        float fh = (float)(rhi - (double)ihi);
        const float inv256 = 1.0f / 256.0f;
        float v0 = (float)s_kv[0] * inv256, v1 = (float)s_kv[1] * inv256;
        float v2 = (float)s_kv[2] * inv256, v3 = (float)s_kv[3] * inv256;
        float lo = v0 + fl * (v1 - v0);
        float hi = v2 + fh * (v3 - v2);
        loArr[ch] = lo;
        scArr[ch] = 1.0f / (hi - lo);
    }
}

// Pass 2: out = mask ? (x - lo) * scale : 0, nontemporal out-stream.
__global__ __launch_bounds__(256) void norm_kernel(
        const float* __restrict__ x, const float* __restrict__ mask,
        const float* __restrict__ loArr, const float* __restrict__ scArr,
        float* __restrict__ out) {
    const int ch    = blockIdx.x / CHUNKS3;
    const int chunk = blockIdx.x % CHUNKS3;
    const int b     = ch / C_;
    const float lo = loArr[ch];
    const float sc = scArr[ch];

    const f32x4* x4 = (const f32x4*)x    + (size_t)ch * (HW / 4);
    const f32x4* m4 = (const f32x4*)mask + (size_t)b  * (HW / 4);
    f32x4*       o4 = (f32x4*)out        + (size_t)ch * (HW / 4);
    const int per_chunk = (HW / 4) / CHUNKS3;   // 2048 float4
    const int base = chunk * per_chunk;

    for (int i = base + threadIdx.x; i < base + per_chunk; i += 256) {
        f32x4 xv = x4[i];
        f32x4 mv = m4[i];
        f32x4 ov;
#pragma unroll
        for (int j = 0; j < 4; ++j)
            ov[j] = (mv[j] > 0.5f) ? (xv[j] - lo) * sc : 0.0f;
        __builtin_nontemporal_store(ov, &o4[i]);
    }
}

extern "C" void kernel_launch(void* const* d_in, const int* in_sizes, int n_in,
                              void* d_out, int out_size, void* d_ws, size_t ws_size,
                              hipStream_t stream) {
    const float* x    = (const float*)d_in[0];
    const float* mask = (const float*)d_in[1];
    float* out = (float*)d_out;

    unsigned* part    = (unsigned*)d_ws;                       // BC*CHUNKS1*1024 u32
    float*    loArr   = (float*)(part + BC * CHUNKS1 * BINS);  // BC
    float*    scArr   = loArr + BC;                            // BC
    unsigned* tickets = (unsigned*)(scArr + BC);               // BC

    // Deterministic ticket base (harness poisons ws to 0xAA between phases).
    hipMemsetAsync(tickets, 0, BC * sizeof(unsigned), stream);

    hist_stats_kernel<<<BC * CHUNKS1, 256, 0, stream>>>(x, mask, part, tickets,
                                                        loArr, scArr);
    norm_kernel      <<<BC * CHUNKS3, 256, 0, stream>>>(x, mask, loArr, scArr, out);
}

// Round 8
// 64.774 us; speedup vs baseline: 2.3639x; 2.3639x over previous
//
#include <hip/hip_runtime.h>

// HFCFilter: median-pad -> (identity hfc) -> per-(b,c) percentile norm on
// 1/256-quantized copy -> mask.
//
// Key facts exploited:
//  * output = mask ? (x - lo)/(hi - lo) : 0   (padding never reaches output)
//  * percentiles on trunc(res*256)/256 data -> exact via histogram rank scan
//  * (int)(x*1024)>>2 == (int)(x*256) exactly in fp32 -> ONE 1024-bin packed
//    histogram serves median (all pixels, lo16) + quantized percentile
//    (masked-in pixels, hi16). Per-block count 32768 < 2^16: no carry.
//  * x in [0,1) -> quantized mass lives in bins [0,256).
//  * R7 lesson: fusing stats via ticket + __threadfence() stalled the whole
//    kernel (VALUBusy 3%, 150us even with data L3-hot) -- device-scope
//    fences on non-coherent per-XCD L2s force per-block L2 writebacks.
//    SEPARATE KERNELS: the launch boundary provides visibility once.
//  * stats is fully parallel (R4): Hillis-Steele scans + crossing search;
//    the masked-out injection at bin kb handled analytically in rank test.
//  * norm uses nontemporal stores (native ext_vector type; HIP float4 class
//    is rejected by the builtin) so the 101 MB out-stream doesn't evict the
//    L3-resident x/mask that norm re-reads.

#define B_       32
#define C_       3
#define BC       (B_ * C_)          // 96 channels
#define HW       (512 * 512)        // 262144 per channel
#define BINS     1024
#define QB       256                // quantized bins actually occupied
#define PCT_     3.0
#define CHUNKS1  8
#define CHUNKS3  32

typedef float f32x4 __attribute__((ext_vector_type(4)));

// Pass 1: per-(channel,chunk) private packed histogram, plain stores to its
// own partial slot (no global atomics, no pre-zeroing needed).
__global__ __launch_bounds__(256) void hist_kernel(
        const float* __restrict__ x, const float* __restrict__ mask,
        unsigned* __restrict__ part) {
    __shared__ unsigned h[BINS];
    const int ch    = blockIdx.x / CHUNKS1;
    const int chunk = blockIdx.x % CHUNKS1;
    const int b     = ch / C_;

    for (int i = threadIdx.x; i < BINS; i += 256) h[i] = 0u;
    __syncthreads();

    const f32x4* x4 = (const f32x4*)x    + (size_t)ch * (HW / 4);
    const f32x4* m4 = (const f32x4*)mask + (size_t)b  * (HW / 4);
    const int per_chunk = (HW / 4) / CHUNKS1;   // 8192 float4
    const int base = chunk * per_chunk;

    for (int i = base + threadIdx.x; i < base + per_chunk; i += 256) {
        f32x4 xv = x4[i];
        f32x4 mv = m4[i];
#pragma unroll
        for (int j = 0; j < 4; ++j) {
            int mb = (int)(xv[j] * 1024.0f);
            mb = mb < 0 ? 0 : (mb > BINS - 1 ? BINS - 1 : mb);
            unsigned add = 1u + ((mv[j] > 0.5f) ? 0x10000u : 0u);
            atomicAdd(&h[mb], add);
        }
    }
    __syncthreads();

    unsigned* dst = part + (size_t)blockIdx.x * BINS;   // [ch][chunk][bin]
    for (int i = threadIdx.x; i < BINS; i += 256) dst[i] = h[i];
}

// Pass 2 (parallel): per channel -- sum partials; prefix-scan totals;
// parallel median crossing-search; prefix-scan masked-in q-bins; parallel
// rank search with analytic injection of the masked-out count at bin kb.
__global__ __launch_bounds__(256) void stats_kernel(
        const unsigned* __restrict__ part,
        float* __restrict__ loArr, float* __restrict__ scArr) {
    __shared__ unsigned tot[BINS];      // all-pixel counts per 1024-bin
    __shared__ unsigned in1024[BINS];   // masked-in counts per 1024-bin
    __shared__ unsigned ps[256];        // scan workspace
    __shared__ unsigned s_mbin[2], s_mcum[2], s_mcnt[2];
    __shared__ unsigned s_qtot;
    __shared__ int      s_kb;
    __shared__ int      s_kv[4];
    const int ch = blockIdx.x;
    const int t  = threadIdx.x;

    const unsigned* p = part + (size_t)ch * CHUNKS1 * BINS;
    for (int bin = t; bin < BINS; bin += 256) {
        unsigned tsum = 0, isum = 0;
#pragma unroll
        for (int c = 0; c < CHUNKS1; ++c) {
            unsigned v = p[(size_t)c * BINS + bin];
            tsum += v & 0xFFFFu;
            isum += v >> 16;
        }
        tot[bin]    = tsum;
        in1024[bin] = isum;
    }
    __syncthreads();

    // ---- scan 1: totals, 4 bins/thread -> median crossing search ----
    unsigned b0 = tot[4*t], b1 = tot[4*t+1], b2 = tot[4*t+2], b3 = tot[4*t+3];
    unsigned s1 = b0 + b1, s2 = s1 + b2, S = s2 + b3;
    ps[t] = S;
    __syncthreads();
#pragma unroll
    for (int d = 1; d < 256; d <<= 1) {
        unsigned v = (t >= d) ? ps[t - d] : 0u;
        __syncthreads();
        ps[t] += v;
        __syncthreads();
    }
    {
        unsigned excl = ps[t] - S;
        unsigned cp[4] = {excl, excl + b0, excl + s1, excl + s2};
        unsigned ci[4] = {excl + b0, excl + s1, excl + s2, excl + S};
        const unsigned tg0 = HW / 2 - 1, tg1 = HW / 2;
#pragma unroll
        for (int j = 0; j < 4; ++j) {
            if (cp[j] <= tg0 && tg0 < ci[j]) {
                s_mbin[0] = 4*t + j; s_mcum[0] = cp[j]; s_mcnt[0] = ci[j] - cp[j];
            }
            if (cp[j] <= tg1 && tg1 < ci[j]) {
                s_mbin[1] = 4*t + j; s_mcum[1] = cp[j]; s_mcnt[1] = ci[j] - cp[j];
            }
        }
    }
    __syncthreads();

    if (t == 0) {
        const unsigned tgs[2] = {HW / 2 - 1, HW / 2};
        float vals[2];
#pragma unroll
        for (int ti = 0; ti < 2; ++ti) {
            float within = ((float)(tgs[ti] - s_mcum[ti]) + 0.5f) / (float)s_mcnt[ti];
            vals[ti] = ((float)s_mbin[ti] + within) * (1.0f / (float)BINS);
        }
        float med = 0.5f * (vals[0] + vals[1]);
        int kb = (int)((med + 0.2f) * 256.0f);
        s_kb = kb < 0 ? 0 : (kb > QB - 1 ? QB - 1 : kb);
    }
    __syncthreads();

    // ---- scan 2: masked-in counts folded to one q-bin per thread ----
    unsigned v = in1024[4*t] + in1024[4*t+1] + in1024[4*t+2] + in1024[4*t+3];
    ps[t] = v;
    __syncthreads();
#pragma unroll
    for (int d = 1; d < 256; d <<= 1) {
        unsigned u = (t >= d) ? ps[t - d] : 0u;
        __syncthreads();
        ps[t] += u;
        __syncthreads();
    }
    unsigned Q = ps[t];
    if (t == 255) s_qtot = Q;
    __syncthreads();

    {
        const unsigned mo = (unsigned)HW - s_qtot;   // masked-out pixel count
        const int kb = s_kb;
        unsigned cp = (Q - v) + ((t >  kb) ? mo : 0u);
        unsigned ci = Q       + ((t >= kb) ? mo : 0u);
        const double rlo = (PCT_ / 100.0) * (double)(HW - 1);
        const double rhi = ((100.0 - PCT_) / 100.0) * (double)(HW - 1);
        const unsigned ilo = (unsigned)rlo, ihi = (unsigned)rhi;
        const unsigned ranks[4] = {ilo, ilo + 1, ihi, ihi + 1};
#pragma unroll
        for (int ri = 0; ri < 4; ++ri)
            if (cp <= ranks[ri] && ranks[ri] < ci) s_kv[ri] = t;
    }
    __syncthreads();

    if (t == 0) {
        const double rlo = (PCT_ / 100.0) * (double)(HW - 1);
        const double rhi = ((100.0 - PCT_) / 100.0) * (double)(HW - 1);
        const unsigned ilo = (unsigned)rlo, ihi = (unsigned)rhi;
        float fl = (float)(rlo - (double)ilo);
        float fh = (float)(rhi - (double)ihi);
        const float inv256 = 1.0f / 256.0f;
        float v0 = (float)s_kv[0] * inv256, v1 = (float)s_kv[1] * inv256;
        float v2 = (float)s_kv[2] * inv256, v3 = (float)s_kv[3] * inv256;
        float lo = v0 + fl * (v1 - v0);
        float hi = v2 + fh * (v3 - v2);
        loArr[ch] = lo;
        scArr[ch] = 1.0f / (hi - lo);
    }
}

// Pass 3: out = mask ? (x - lo) * scale : 0, nontemporal out-stream.
__global__ __launch_bounds__(256) void norm_kernel(
        const float* __restrict__ x, const float* __restrict__ mask,
        const float* __restrict__ loArr, const float* __restrict__ scArr,
        float* __restrict__ out) {
    const int ch    = blockIdx.x / CHUNKS3;
    const int chunk = blockIdx.x % CHUNKS3;
    const int b     = ch / C_;
    const float lo = loArr[ch];
    const float sc = scArr[ch];

    const f32x4* x4 = (const f32x4*)x    + (size_t)ch * (HW / 4);
    const f32x4* m4 = (const f32x4*)mask + (size_t)b  * (HW / 4);
    f32x4*       o4 = (f32x4*)out        + (size_t)ch * (HW / 4);
    const int per_chunk = (HW / 4) / CHUNKS3;   // 2048 float4
    const int base = chunk * per_chunk;

    for (int i = base + threadIdx.x; i < base + per_chunk; i += 256) {
        f32x4 xv = x4[i];
        f32x4 mv = m4[i];
        f32x4 ov;
#pragma unroll
        for (int j = 0; j < 4; ++j)
            ov[j] = (mv[j] > 0.5f) ? (xv[j] - lo) * sc : 0.0f;
        __builtin_nontemporal_store(ov, &o4[i]);
    }
}

extern "C" void kernel_launch(void* const* d_in, const int* in_sizes, int n_in,
                              void* d_out, int out_size, void* d_ws, size_t ws_size,
                              hipStream_t stream) {
    const float* x    = (const float*)d_in[0];
    const float* mask = (const float*)d_in[1];
    float* out = (float*)d_out;

    unsigned* part  = (unsigned*)d_ws;                        // BC*CHUNKS1*1024 u32 = 3.1 MB
    float*    loArr = (float*)(part + BC * CHUNKS1 * BINS);   // BC
    float*    scArr = loArr + BC;                             // BC

    hist_kernel <<<BC * CHUNKS1, 256, 0, stream>>>(x, mask, part);
    stats_kernel<<<BC,           256, 0, stream>>>(part, loArr, scArr);
    norm_kernel <<<BC * CHUNKS3, 256, 0, stream>>>(x, mask, loArr, scArr, out);
}